// Round 1
// baseline (299.004 us; speedup 1.0000x reference)
//
#include <hip/hip_runtime.h>
#include <cstdint>
#include <cstddef>

#define CIN   128
#define COUT  256
#define HW    64
#define NSP   4096      // 64*64 spatial
#define KTOT  1152      // CIN*9
#define BATCH 32
#define PDROP 0.2f
#define LDT   40        // fallback conv LDS stride (bf16 elems)

__device__ __forceinline__ unsigned short f2bf(float f) {
    unsigned int u = __builtin_bit_cast(unsigned int, f);
    u += 0x7fffu + ((u >> 16) & 1u);   // round-to-nearest-even
    return (unsigned short)(u >> 16);
}

// 128 B of guaranteed zeros for OOB halo DMA source (never written)
__device__ __align__(16) unsigned short g_zeros[64] = {0};

// async global->LDS, 16 B per lane; LDS dest = wave-uniform base + lane*16
__device__ __forceinline__ void gl_lds16(const unsigned short* g, unsigned short* l) {
    __builtin_amdgcn_global_load_lds(
        (const __attribute__((address_space(1))) unsigned int*)g,
        (__attribute__((address_space(3))) unsigned int*)l,
        16, 0, 0);
}

// ---------------------------------------------------------------------------
// Fused pre-pass (single launch):
//  blocks [0,4096):   per-sample masked bf16 weights, tap-major wt[bo][r*128+i]
//                     (2 bo per block). Thread-per-channel: LDS writes are
//                     2-way bank-aliased (free), no div-by-9.
//  blocks [4096,6144): x NCHW fp32 -> xt[b][hw][ch] bf16 (NHWC).
//                     Channel-pair u32 tile, stride 65 u32 (bank = row+col):
//                     2-way free on both write and read (old layout was
//                     16-way conflicted on writes).
__global__ __launch_bounds__(256) void prepass(
        const float* __restrict__ weight, const float* __restrict__ u_w,
        const float* __restrict__ x,
        unsigned short* __restrict__ wt, unsigned short* __restrict__ xt)
{
    __shared__ unsigned int shp[64 * 65];          // 16640 B (>= 2*1152 u16)
    unsigned short* sh16 = reinterpret_cast<unsigned short*>(shp);
    const int t256 = threadIdx.x;

    if (blockIdx.x < 4096) {
        const int half = t256 >> 7;                // 0/1: which bo
        const int i    = t256 & 127;               // channel
        const int bo   = blockIdx.x * 2 + half;    // b*COUT + o
        const int o    = bo & (COUT - 1);
        unsigned short* tile = sh16 + half * KTOT;
        const float* wsrc = weight + (size_t)o  * KTOT + i * 9;
        const float* usrc = u_w    + (size_t)bo * KTOT + i * 9;
        float wv9[9], uv9[9];
        #pragma unroll
        for (int r = 0; r < 9; ++r) { wv9[r] = wsrc[r]; uv9[r] = usrc[r]; }
        #pragma unroll
        for (int r = 0; r < 9; ++r)               // bank = (i/2)%32: 2-way free
            tile[r * CIN + i] = f2bf((uv9[r] > PDROP) ? wv9[r] : 0.f);
        __syncthreads();
        const uint4* src = reinterpret_cast<const uint4*>(tile);
        uint4* dst = reinterpret_cast<uint4*>(wt + (size_t)bo * KTOT);
        dst[i] = src[i];                           // 144 uint4 per tile
        if (i < 16) dst[128 + i] = src[128 + i];
    } else {
        const int bidx = blockIdx.x - 4096;
        const int b    = bidx >> 6;
        const int hw0  = (bidx & 63) * 64;
        const int ib   = t256 >> 4;                // 0..15
        const int hw4  = (t256 & 15) * 4;          // local hw row group
        #pragma unroll
        for (int j = 0; j < 4; ++j) {
            const int p = ib + 16 * j;             // channel-pair 0..63
            const float4 v0 = *reinterpret_cast<const float4*>(
                x + ((size_t)(b * CIN + 2 * p)) * NSP + hw0 + hw4);
            const float4 v1 = *reinterpret_cast<const float4*>(
                x + ((size_t)(b * CIN + 2 * p + 1)) * NSP + hw0 + hw4);
            const float e0[4] = {v0.x, v0.y, v0.z, v0.w};
            const float e1[4] = {v1.x, v1.y, v1.z, v1.w};
            #pragma unroll
            for (int c = 0; c < 4; ++c) {
                const unsigned int val =
                    (unsigned int)f2bf(e0[c]) | ((unsigned int)f2bf(e1[c]) << 16);
                // bank = ((hw4+c)*65 + p) % 32 = (hw4+c+p) % 32 -> 2-way free
                shp[(hw4 + c) * 65 + p] = val;
            }
        }
        __syncthreads();
        #pragma unroll
        for (int j = 0; j < 4; ++j) {
            const int idx  = j * 256 + t256;       // 0..1023
            const int row  = idx >> 4;             // hw_loc 0..63
            const int part = idx & 15;             // 16 B chunk (4 u32 pairs)
            uint4 v;
            v.x = shp[row * 65 + part * 4 + 0];    // 4x b32, 2-way free
            v.y = shp[row * 65 + part * 4 + 1];
            v.z = shp[row * 65 + part * 4 + 2];
            v.w = shp[row * 65 + part * 4 + 3];
            *reinterpret_cast<uint4*>(
                xt + ((size_t)(b * NSP + hw0 + row)) * CIN + part * 8) = v;
        }
    }
}

// ---------------------------------------------------------------------------
// Main conv v5: implicit GEMM, LDS-resident x-tile + DOUBLE-BUFFERED A-tiles
// with counted-vmcnt software pipeline (T3+T4) and s_setprio MFMA cluster (T5).
// Per iteration it = slab*9 + tap (18 total):
//   [it==9: issue X-DMA slab1]  [issue A-DMA(it+1) into As[(it+1)&1]]
//   s_waitcnt vmcnt(4)   (A(it) + any X retired; A(it+1) stays IN FLIGHT)
//   s_barrier  ->  ds_read frags + 32 MFMA (setprio 1)  ->  s_barrier
// End barrier of it-1 protects As[(it+1)&1] from the prefetch overwrite.
// XCD-clustered block swizzle: all 64 blocks of one sample land on one XCD
// (concurrent L2 working set wt 0.6 MB + xt 1 MB < 4 MB).
__global__ __launch_bounds__(256, 2) void conv_v5(
        const unsigned short* __restrict__ wt,
        const unsigned short* __restrict__ xt,
        const float* __restrict__ bias, const float* __restrict__ u_b,
        float* __restrict__ out)
{
    using frag  = __attribute__((ext_vector_type(8))) short;
    using f32x4 = __attribute__((ext_vector_type(4))) float;

    __shared__ unsigned short Xs[4 * 66 * 64];     // 33792 B resident x-tile
    __shared__ unsigned short As[2][128 * 64];     // 2 x 16384 B A double-buffer

    const int tid  = threadIdx.x;
    const int lane = tid & 63;
    const int q    = lane >> 4;
    const int l15  = lane & 15;
    const int wv   = tid >> 6;
    const int wm   = (wv >> 1) * 64;
    const int wn   = (wv & 1) * 64;
    const int wnrow = wn >> 6;                     // 0 or 1: tile spatial row

    // ---- XCD-clustered bijective swizzle (grid = 32 x 2 x 32 = 2048, %8==0)
    const int f   = blockIdx.x + 32 * blockIdx.y + 64 * blockIdx.z;
    const int wid = (f & 7) * 256 + (f >> 3);
    const int b   = wid >> 6;
    const int m0  = ((wid >> 5) & 1) * 128;
    const int n0  = (wid & 31) * 128;
    const int ph0 = n0 >> 6;                       // first global image row

    const unsigned short* wtb = wt + (size_t)(b * COUT + m0) * KTOT;
    const unsigned short* xtb = xt + (size_t)b * NSP * CIN;

    // ---- A-DMA map: lane -> (row r8 in group of 8, phys chunk p8)
    const int r8 = lane >> 3;
    const int p8 = lane & 7;
    const int cx = p8 ^ r8;                        // logical chunk (swizzle)
    const unsigned short* gA[4];
    #pragma unroll
    for (int j = 0; j < 4; ++j) {
        const int row = wv * 32 + j * 8 + r8;      // 0..127
        gA[j] = wtb + (size_t)row * KTOT + cx * 8;
    }

    // ---- X-DMA map: wave wv stages X row rr=wv (global row ph0-1+wv).
    const int kcl = (lane & 7) ^ ((1 + (lane >> 3)) & 7);
    const int xsrc_lane = (lane >> 3) * CIN + kcl * 8;   // u16 offset in xt row
    const int hhx = ph0 - 1 + wv;
    const bool vrow = ((unsigned)hhx < 64u);
    unsigned short* const xdst = &Xs[(wv * 66 + 1) * 64];

    // ---- frag-read constants
    const int l7 = l15 & 7;
    const int physk0 = q ^ l7;                     // A ki=0 phys chunk
    const int physk1 = (4 + q) ^ l7;               // A ki=1
    const int a_base = (wm + l15) * 64;
    int xoff[4];
    #pragma unroll
    for (int ni = 0; ni < 4; ++ni) xoff[ni] = (ni * 16 + l15 + 1) * 64;
    int xr[3][2];
    #pragma unroll
    for (int dxi = 0; dxi < 3; ++dxi)
        #pragma unroll
        for (int ki = 0; ki < 2; ++ki)
            xr[dxi][ki] = ((ki * 4 + q) ^ ((l15 + dxi) & 7)) * 8;

    f32x4 acc[4][4];
    #pragma unroll
    for (int i = 0; i < 4; ++i)
        #pragma unroll
        for (int j = 0; j < 4; ++j)
            acc[i][j] = (f32x4){0.f, 0.f, 0.f, 0.f};

    // ---- zero the column-halo cells of Xs once (cc=0 and cc=65, all 4 rows)
    {
        const int cell = tid >> 5;                 // 0..7
        const int rr   = cell >> 1;
        const int cc   = (cell & 1) ? 65 : 0;
        *reinterpret_cast<unsigned int*>(
            &Xs[(rr * 66 + cc) * 64 + (tid & 31) * 2]) = 0u;
    }

    // ---- staging helpers
    auto stage_a = [&](int k0, int buf) {
        #pragma unroll
        for (int j = 0; j < 4; ++j)
            gl_lds16(gA[j] + k0, &As[buf][(wv * 32 + j * 8) * 64]);
    };
    auto stage_x = [&](int i0) {
        const unsigned short* sx = vrow
            ? xtb + (size_t)hhx * HW * CIN + i0 + xsrc_lane
            : g_zeros;
        #pragma unroll
        for (int g = 0; g < 8; ++g)
            gl_lds16(vrow ? (sx + g * 8 * CIN) : sx, xdst + g * 512);
    };

    // ---- prologue: A(it=0) into buf0, X slab0.  outstanding = 12 loads/wave
    stage_a(0, 0);
    stage_x(0);

    #pragma unroll
    for (int it = 0; it < 18; ++it) {
        const int tap = it % 9;
        const int cur = it & 1;

        // Xs reads of slab0 finished at it=8's end barrier -> safe to restage
        if (it == 9) stage_x(64);

        // prefetch next A-tile; its buffer was last read at it-1 (end barrier)
        if (it < 17) {
            const int nit = it + 1;
            stage_a((nit % 9) * 128 + (nit / 9) * 64, nit & 1);
        }

        // counted wait: retire A(it) (+X at slab entry), keep A(it+1) in flight
        if (it == 0)      asm volatile("s_waitcnt vmcnt(4) lgkmcnt(0)" ::: "memory");
        else if (it < 17) asm volatile("s_waitcnt vmcnt(4)" ::: "memory");
        else              asm volatile("s_waitcnt vmcnt(0)" ::: "memory");
        __builtin_amdgcn_s_barrier();              // data-ready barrier

        const int dy  = tap / 3 - 1;
        const int dx  = tap - 3 * (tap / 3) - 1;
        const int dxi = dx + 1;
        const int cb  = (wnrow + dy + 1) * 4224 + dx * 64;  // 66*64 = 4224

        __builtin_amdgcn_s_setprio(1);
        #pragma unroll
        for (int ki = 0; ki < 2; ++ki) {
            const int pk = ki ? physk1 : physk0;
            frag af[4], bfr[4];
            #pragma unroll
            for (int mi = 0; mi < 4; ++mi)
                af[mi] = *reinterpret_cast<const frag*>(
                    &As[cur][a_base + mi * 1024 + pk * 8]);
            #pragma unroll
            for (int ni = 0; ni < 4; ++ni)
                bfr[ni] = *reinterpret_cast<const frag*>(
                    &Xs[cb + xoff[ni] + xr[dxi][ki]]);
            #pragma unroll
            for (int mi = 0; mi < 4; ++mi)
                #pragma unroll
                for (int ni = 0; ni < 4; ++ni)
                    acc[mi][ni] = __builtin_amdgcn_mfma_f32_16x16x32_bf16(
                        af[mi], bfr[ni], acc[mi][ni], 0, 0, 0);
        }
        __builtin_amdgcn_s_setprio(0);

        if (it < 17) __builtin_amdgcn_s_barrier(); // reads done -> next prefetch safe
    }

    // ---- epilogue: D row=(q*4+reg), col=l15 ; add dropped-out bias
    float* ob = out + (size_t)b * COUT * NSP;
    #pragma unroll
    for (int mi = 0; mi < 4; ++mi) {
        #pragma unroll
        for (int rg = 0; rg < 4; ++rg) {
            const int o  = m0 + wm + mi * 16 + q * 4 + rg;
            const float bvv = (u_b[b * COUT + o] > PDROP) ? bias[o] : 0.f;
            float* orow = ob + (size_t)o * NSP + n0 + wn + l15;
            #pragma unroll
            for (int ni = 0; ni < 4; ++ni)
                orow[ni * 16] = acc[mi][ni][rg] + bvv;
        }
    }
}

// ---------------------------------------------------------------------------
// Fallback (round-1 kernel): used only if workspace is too small.
template<bool USE_WS>
__global__ __launch_bounds__(256) void conv_fb(
        const float* __restrict__ x, const float* __restrict__ weight,
        const float* __restrict__ bias, const float* __restrict__ u_w,
        const float* __restrict__ u_b, const unsigned short* __restrict__ wt,
        float* __restrict__ out)
{
    using frag  = __attribute__((ext_vector_type(8))) short;
    using f32x4 = __attribute__((ext_vector_type(4))) float;

    __shared__ unsigned short As[128 * LDT];
    __shared__ unsigned short Bs[128 * LDT];

    const int tid  = threadIdx.x;
    const int lane = tid & 63;
    const int q    = lane >> 4;
    const int l15  = lane & 15;
    const int wv   = tid >> 6;
    const int wm   = (wv >> 1) * 64;
    const int wn   = (wv & 1) * 64;

    const int b  = blockIdx.z;
    const int m0 = blockIdx.y * 128;
    const int n0 = blockIdx.x * 128;

    const int arow = tid >> 1;
    const int acol = (tid & 1) * 16;
    const int pn = tid & 127;
    const int kh = (tid >> 7) * 16;
    const int p  = n0 + pn;
    const int ph = p >> 6;
    const int pw = p & 63;

    const float* xb = x + (size_t)b * CIN * NSP;

    f32x4 acc[4][4];
    #pragma unroll
    for (int i = 0; i < 4; ++i)
        #pragma unroll
        for (int j = 0; j < 4; ++j)
            acc[i][j] = (f32x4){0.f, 0.f, 0.f, 0.f};

    const int a_rd = (wm + l15) * LDT + q * 8;
    const int b_rd = (wn + l15) * LDT + q * 8;

    for (int s = 0; s < 36; ++s) {
        const int r  = s >> 2;
        const int i0 = (s & 3) * 32;
        const int k0 = s * 32;

        uint4 av0, av1;
        float aw[16], au[16];
        if (USE_WS) {
            const uint4* src = reinterpret_cast<const uint4*>(
                wt + ((size_t)(b * COUT + m0 + arow)) * KTOT + k0 + acol);
            av0 = src[0];
            av1 = src[1];
        } else {
            const float* wsrc = weight + (size_t)(m0 + arow) * KTOT;
            const float* usrc = u_w + (size_t)(b * COUT + m0 + arow) * KTOT;
            #pragma unroll
            for (int ii = 0; ii < 16; ++ii) {
                const int kk = (i0 + acol + ii) * 9 + r;
                aw[ii] = wsrc[kk];
                au[ii] = usrc[kk];
            }
        }

        const int hh = ph + (r / 3) - 1;
        const int ww = pw + (r % 3) - 1;
        float bx[16];
        #pragma unroll
        for (int j = 0; j < 16; ++j) bx[j] = 0.f;
        if (((unsigned)hh < 64u) && ((unsigned)ww < 64u)) {
            const float* xsrc = xb + (size_t)(i0 + kh) * NSP + hh * HW + ww;
            #pragma unroll
            for (int j = 0; j < 16; ++j) bx[j] = xsrc[(size_t)j * NSP];
        }

        __syncthreads();

        if (USE_WS) {
            uint4* d = reinterpret_cast<uint4*>(&As[arow * LDT + acol]);
            d[0] = av0; d[1] = av1;
        } else {
            union { unsigned short u16[16]; uint4 v[2]; } tu;
            #pragma unroll
            for (int ii = 0; ii < 16; ++ii)
                tu.u16[ii] = f2bf((au[ii] > PDROP) ? aw[ii] : 0.f);
            uint4* d = reinterpret_cast<uint4*>(&As[arow * LDT + acol]);
            d[0] = tu.v[0]; d[1] = tu.v[1];
        }
        {
            union { unsigned short u16[16]; uint4 v[2]; } tu;
            #pragma unroll
            for (int j = 0; j < 16; ++j) tu.u16[j] = f2bf(bx[j]);
            uint4* d = reinterpret_cast<uint4*>(&Bs[pn * LDT + kh]);
            d[0] = tu.v[0]; d[1] = tu.v[1];
        }

        __syncthreads();

        frag af[4], bfr[4];
        #pragma unroll
        for (int mi = 0; mi < 4; ++mi)
            af[mi] = *reinterpret_cast<const frag*>(&As[a_rd + mi * 16 * LDT]);
        #pragma unroll
        for (int ni = 0; ni < 4; ++ni)
            bfr[ni] = *reinterpret_cast<const frag*>(&Bs[b_rd + ni * 16 * LDT]);
        #pragma unroll
        for (int mi = 0; mi < 4; ++mi)
            #pragma unroll
            for (int ni = 0; ni < 4; ++ni)
                acc[mi][ni] = __builtin_amdgcn_mfma_f32_16x16x32_bf16(
                    af[mi], bfr[ni], acc[mi][ni], 0, 0, 0);
    }

    float* ob = out + (size_t)b * COUT * NSP;
    #pragma unroll
    for (int mi = 0; mi < 4; ++mi) {
        #pragma unroll
        for (int rg = 0; rg < 4; ++rg) {
            const int o = m0 + wm + mi * 16 + q * 4 + rg;
            const float bvv = (u_b[b * COUT + o] > PDROP) ? bias[o] : 0.f;
            float* orow = ob + (size_t)o * NSP + n0 + wn + l15;
            #pragma unroll
            for (int ni = 0; ni < 4; ++ni)
                orow[ni * 16] = acc[mi][ni][rg] + bvv;
        }
    }
}

extern "C" void kernel_launch(void* const* d_in, const int* in_sizes, int n_in,
                              void* d_out, int out_size, void* d_ws, size_t ws_size,
                              hipStream_t stream)
{
    const float* x      = (const float*)d_in[0];
    const float* weight = (const float*)d_in[1];
    const float* bias   = (const float*)d_in[2];
    const float* u_w    = (const float*)d_in[3];
    const float* u_b    = (const float*)d_in[4];
    float* out = (float*)d_out;

    const size_t wt_bytes = (size_t)BATCH * COUT * KTOT * sizeof(unsigned short); // 18.87 MB
    const size_t xt_bytes = (size_t)BATCH * NSP * CIN * sizeof(unsigned short);   // 33.55 MB
    dim3 grid(NSP / 128, COUT / 128, BATCH);   // 32 x 2 x 32 = 2048 blocks

    if (ws_size >= wt_bytes + xt_bytes) {
        unsigned short* wtp = (unsigned short*)d_ws;
        unsigned short* xtp = (unsigned short*)((char*)d_ws + wt_bytes);
        prepass<<<4096 + 2048, 256, 0, stream>>>(weight, u_w, x, wtp, xtp);
        conv_v5<<<grid, 256, 0, stream>>>(wtp, xtp, bias, u_b, out);
    } else if (ws_size >= wt_bytes) {
        unsigned short* wtp = (unsigned short*)d_ws;
        // reuse prepass weight half only
        prepass<<<4096, 256, 0, stream>>>(weight, u_w, x, wtp, nullptr);
        conv_fb<true><<<grid, 256, 0, stream>>>(x, weight, bias, u_w, u_b, wtp, out);
    } else {
        conv_fb<false><<<grid, 256, 0, stream>>>(x, weight, bias, u_w, u_b, nullptr, out);
    }
}